// Round 8
// baseline (682.346 us; speedup 1.0000x reference)
//
#include <hip/hip_runtime.h>
#include <cmath>

// ---- problem dims (fixed per reference) ----
#define YCH 8        // y_channels
#define NTR 16       // trials
#define LLEN 4096    // trial length
#define CK  16       // kernels per channel
#define KS  64       // kernel size
#define ENC 4033     // LLEN - KS + 1
#define NP  128      // YCH*NTR independent problems
#define INV_LIP 0.1f     // 1/10
#define THRESH 0.01f     // LAM/LIP = 0.1/10

#define XW4 272          // float4s per 1088-float window tile

// B over [gi4, gi4+3], zero outside [0, ENC):  B = a + gamma*(a - p)
__device__ __forceinline__ float4 loadB4(const float* __restrict__ A,
                                         const float* __restrict__ P,
                                         float gamma, size_t coff, int gi4)
{
    if (gi4 >= 0 && gi4 + 3 < ENC) {
        float4 a = *(const float4*)(A + coff + gi4);
        float4 p = *(const float4*)(P + coff + gi4);
        return make_float4(fmaf(gamma, a.x - p.x, a.x),
                           fmaf(gamma, a.y - p.y, a.y),
                           fmaf(gamma, a.z - p.z, a.z),
                           fmaf(gamma, a.w - p.w, a.w));
    }
    float r[4];
    #pragma unroll
    for (int j = 0; j < 4; ++j) {
        int gi = gi4 + j;
        if (gi >= 0 && gi < ENC) {
            float a = A[coff + gi], p = P[coff + gi];
            r[j] = fmaf(gamma, a - p, a);
        } else r[j] = 0.f;
    }
    return make_float4(r[0], r[1], r[2], r[3]);
}

// =====================================================================
// resid_quad: part[q][p][t] = sum_{c in quad q, k} B[p,c,t-k]*H[ch,c,k]
// block = (ttile=1024, q, p) -> grid (4,4,128) x 256 thr, 4 outputs/thread.
// Stage quad's 4 B-windows (momentum folded) in LDS, ONE barrier, then a
// ROLLING NAMED-REGISTER window (A,B float4 pair) per channel -- no
// indexable array, so the compiler cannot demote operands to LDS re-reads.
// Identity: acc[j] += xs[4t+64+j-k]*h[k]; with k=63-4g-m this is
//   acc[j] += w[1+m+j]*hc[15-g][3-m],  w = {A.xyzw, B.xyzw}, A=xr[g].
// =====================================================================
__global__ __launch_bounds__(256) void resid_quad(
    const float* __restrict__ H,
    const float* __restrict__ Acur, const float* __restrict__ Aprev,
    float gamma, float* __restrict__ part)
{
    __shared__ __align__(16) float xs[4 * 1088];  // 17408 B
    __shared__ __align__(16) float hs[4 * KS];    //  1024 B
    const int tid = threadIdx.x;
    const int t0  = blockIdx.x * 1024;
    const int c0  = blockIdx.y * 4;
    const int p   = blockIdx.z;
    const int ch  = p >> 4;

    if (tid < 64)
        ((float4*)hs)[tid] = ((const float4*)(H + ((size_t)ch * CK + c0) * KS))[tid];

    const size_t pbase = (size_t)p * CK * ENC;
    // stage 4 channels x 272 f4 = 1088 f4 (4.25 per thread)
    #pragma unroll
    for (int s = 0; s < 5; ++s) {
        int l4 = tid + 256 * s;
        if (l4 < 4 * XW4) {
            int c   = l4 / XW4;
            int off = l4 - c * XW4;
            ((float4*)xs)[l4] = loadB4(Acur, Aprev, gamma,
                                       pbase + (size_t)(c0 + c) * ENC,
                                       t0 - 64 + 4 * off);
        }
    }
    __syncthreads();

    float acc[4] = {0.f, 0.f, 0.f, 0.f};

    #pragma unroll
    for (int cc = 0; cc < 4; ++cc) {
        const float4* xr = (const float4*)(xs + cc * 1088) + tid;
        const float4* hc = (const float4*)(hs + cc * KS);
        float4 A = xr[0], B = xr[1];
        #pragma unroll
        for (int g = 0; g < 16; ++g) {
            float4 h4 = hc[15 - g];
            float hh[4] = {h4.w, h4.z, h4.y, h4.x};   // hh[m] = h[63-4g-m]
            float w[8]  = {A.x, A.y, A.z, A.w, B.x, B.y, B.z, B.w};
            #pragma unroll
            for (int m = 0; m < 4; ++m)
                #pragma unroll
                for (int j = 0; j < 4; ++j)
                    acc[j] = fmaf(w[1 + m + j], hh[m], acc[j]);
            A = B;
            if (g < 15) B = xr[g + 2];
        }
    }

    const int t = t0 + 4 * tid;
    *(float4*)(part + ((size_t)blockIdx.y * NP + p) * LLEN + t) =
        make_float4(acc[0], acc[1], acc[2], acc[3]);
}

// =====================================================================
// fista_quad (unchanged, ~17us, near cache-traffic floor):
//   staging: rs = y - sum_q part[q]  (reduce fused; first: rs = y)
//   g[c,i] = sum_k rs[i+k]*H[ch,c,k];  x_new = relu(B + g/LIP - thr)
// =====================================================================
__global__ __launch_bounds__(256) void fista_quad(
    const float* __restrict__ y, const float* __restrict__ part,
    const float* __restrict__ H,
    const float* __restrict__ Acur, const float* __restrict__ Aprev,
    float gamma, int first, float* __restrict__ Anext)
{
    __shared__ __align__(16) float rs[XW4 * 4];
    __shared__ __align__(16) float hs[4 * KS];
    const int tid = threadIdx.x;
    const int i0  = blockIdx.x * 1024;
    const int c0  = blockIdx.y * 4;
    const int p   = blockIdx.z;
    const int n = p & 15, ch = p >> 4;

    if (tid < 64)
        ((float4*)hs)[tid] = ((const float4*)(H + ((size_t)ch * CK + c0) * KS))[tid];

    const float* ybase = y + ((size_t)n * YCH + ch) * LLEN;
    #pragma unroll
    for (int s = 0; s < 2; ++s) {
        int l4 = tid + 256 * s;
        if (l4 < XW4) {
            int gi4 = i0 + 4 * l4;
            float4 v;
            if (gi4 + 3 < LLEN) {
                v = *(const float4*)(ybase + gi4);
                if (!first) {
                    #pragma unroll
                    for (int q = 0; q < 4; ++q) {
                        float4 pv = *(const float4*)(part + ((size_t)q * NP + p) * LLEN + gi4);
                        v.x -= pv.x; v.y -= pv.y; v.z -= pv.z; v.w -= pv.w;
                    }
                }
            } else {
                float r[4];
                #pragma unroll
                for (int j = 0; j < 4; ++j) {
                    int gi = gi4 + j;
                    if (gi < LLEN) {
                        float t = ybase[gi];
                        if (!first) {
                            #pragma unroll
                            for (int q = 0; q < 4; ++q)
                                t -= part[((size_t)q * NP + p) * LLEN + gi];
                        }
                        r[j] = t;
                    } else r[j] = 0.f;
                }
                v = make_float4(r[0], r[1], r[2], r[3]);
            }
            ((float4*)rs)[l4] = v;
        }
    }
    __syncthreads();

    // hoisted register window rs[4*tid .. 4*tid+67], shared by 4 channels
    float wf[68];
    const float4* rr = (const float4*)rs + tid;
    #pragma unroll
    for (int q = 0; q < 17; ++q) {
        float4 t4 = rr[q];
        wf[4*q] = t4.x; wf[4*q+1] = t4.y; wf[4*q+2] = t4.z; wf[4*q+3] = t4.w;
    }

    const int i = i0 + 4 * tid;
    const size_t pb = (size_t)p * CK * ENC;
    const bool vec = (i + 3 < ENC);

    float4 a0 = make_float4(0,0,0,0), p0 = make_float4(0,0,0,0);
    if (!first && vec) {
        a0 = *(const float4*)(Acur  + pb + (size_t)c0 * ENC + i);
        p0 = *(const float4*)(Aprev + pb + (size_t)c0 * ENC + i);
    }

    for (int cc = 0; cc < 4; ++cc) {
        float4 a1 = make_float4(0,0,0,0), p1 = make_float4(0,0,0,0);
        if (!first && vec && cc < 3) {
            a1 = *(const float4*)(Acur  + pb + (size_t)(c0 + cc + 1) * ENC + i);
            p1 = *(const float4*)(Aprev + pb + (size_t)(c0 + cc + 1) * ENC + i);
        }

        float acc[4] = {0.f, 0.f, 0.f, 0.f};
        const float4* hc = (const float4*)(hs + cc * KS);
        #pragma unroll
        for (int g = 0; g < 16; ++g) {
            float4 h4 = hc[g];
            float hh[4] = {h4.x, h4.y, h4.z, h4.w};
            #pragma unroll
            for (int m = 0; m < 4; ++m) {
                const int k = 4 * g + m;
                #pragma unroll
                for (int j = 0; j < 4; ++j)
                    acc[j] = fmaf(wf[k + j], hh[m], acc[j]);
            }
        }

        const size_t idx = pb + (size_t)(c0 + cc) * ENC + i;
        if (vec) {
            float B[4] = {0.f, 0.f, 0.f, 0.f};
            if (!first) {
                float av[4] = {a0.x, a0.y, a0.z, a0.w};
                float pv[4] = {p0.x, p0.y, p0.z, p0.w};
                #pragma unroll
                for (int j = 0; j < 4; ++j) B[j] = fmaf(gamma, av[j] - pv[j], av[j]);
            }
            float4 o;
            o.x = fmaxf(fmaf(acc[0], INV_LIP, B[0]) - THRESH, 0.f);
            o.y = fmaxf(fmaf(acc[1], INV_LIP, B[1]) - THRESH, 0.f);
            o.z = fmaxf(fmaf(acc[2], INV_LIP, B[2]) - THRESH, 0.f);
            o.w = fmaxf(fmaf(acc[3], INV_LIP, B[3]) - THRESH, 0.f);
            *(float4*)(Anext + idx) = o;
        } else if (i < ENC) {
            #pragma unroll
            for (int j = 0; j < 4; ++j) {
                if (i + j < ENC) {
                    float B = 0.f;
                    if (!first) {
                        float a = Acur[idx + j], pp = Aprev[idx + j];
                        B = fmaf(gamma, a - pp, a);
                    }
                    Anext[idx + j] = fmaxf(fmaf(acc[j], INV_LIP, B) - THRESH, 0.f);
                }
            }
        }
        a0 = a1; p0 = p1;
    }
}

// =====================================================================
extern "C" void kernel_launch(void* const* d_in, const int* in_sizes, int n_in,
                              void* d_out, int out_size, void* d_ws, size_t ws_size,
                              hipStream_t stream)
{
    const float* y = (const float*)d_in[0];   // [NTR, YCH, LLEN]
    const float* H = (const float*)d_in[1];   // [YCH, CK, 1, KS]
    const size_t XSZ = (size_t)NP * CK * ENC; // 8,259,584 floats

    float* bufA = (float*)d_ws;               // A_t for even t
    float* bufB = (float*)d_out;              // A_t for odd t (A9 -> d_out)
    float* part = bufA + XSZ;                 // [4][NP][LLEN] partial synth sums

    double s[11]; s[0] = 1.0;
    for (int t = 1; t <= 10; ++t) s[t] = 0.5 * (1.0 + sqrt(1.0 + 4.0 * s[t-1] * s[t-1]));

    dim3 gR(4, 4, NP), gF(4, 4, NP);

    for (int t = 0; t < 10; ++t) {
        float gamma = (t == 0) ? 0.f : (float)((s[t-1] - 1.0) / s[t]);
        float* Anext       = (t & 1) ? bufB : bufA;
        const float* Acur  = (t & 1) ? bufA : bufB;              // A_{t-1}
        const float* Aprev = (t <= 1) ? Acur                     // gamma==0, unused
                                      : ((t & 1) ? bufB : bufA); // A_{t-2}
        if (t == 0) {
            // B_0 = 0 => res = y; fuse into update kernel (first=1)
            fista_quad<<<gF, 256, 0, stream>>>(y, part, H, bufA, bufA, 0.f, 1, bufA);
        } else {
            resid_quad<<<gR, 256, 0, stream>>>(H, Acur, Aprev, gamma, part);
            fista_quad<<<gF, 256, 0, stream>>>(y, part, H, Acur, Aprev, gamma, 0, Anext);
        }
    }
}